// Round 3
// baseline (1447.720 us; speedup 1.0000x reference)
//
#include <hip/hip_runtime.h>
#include <hip/hip_bf16.h>

#define Vn 25000
#define En 100000
#define NODE_IN 74
#define EDGE_IN 12
#define OUTD 64
#define EHID 128
#define NUM_STEPS 6

#define HPAD 68  // h_t row pitch (floats)

typedef __attribute__((ext_vector_type(8))) _Float16 half8;
typedef __attribute__((ext_vector_type(4))) float floatx4;

// h[v,o] = relu(node[v,:] @ Wp + bp)   [V,74]@[74,64]  (all fp32)
__global__ void proj_kernel(const float* __restrict__ node,
                            const float* __restrict__ Wp,
                            const float* __restrict__ bp,
                            float* __restrict__ h) {
  __shared__ float nf[NODE_IN];
  int v = blockIdx.x;
  int o = threadIdx.x;  // 64
  for (int i = o; i < NODE_IN; i += 64) nf[i] = node[(size_t)v * NODE_IN + i];
  __syncthreads();
  float acc = bp[o];
  for (int i = 0; i < NODE_IN; ++i) acc = fmaf(nf[i], Wp[i * OUTD + o], acc);
  h[(size_t)v * OUTD + o] = fmaxf(acc, 0.0f);
}

// f[e,k] = relu(edge[e,:] @ We1 + be1)   [E,12]@[12,128] fp32, stored f16
__global__ void edge_kernel(const float* __restrict__ ef,
                            const float* __restrict__ We1,
                            const float* __restrict__ be1,
                            _Float16* __restrict__ f) {
  __shared__ float es[EDGE_IN];
  int e = blockIdx.x;
  int k = threadIdx.x;  // 128
  if (k < EDGE_IN) es[k] = ef[(size_t)e * EDGE_IN + k];
  __syncthreads();
  float acc = be1[k];
  for (int j = 0; j < EDGE_IN; ++j) acc = fmaf(es[j], We1[j * EHID + k], acc);
  f[(size_t)e * EHID + k] = (_Float16)fmaxf(acc, 0.0f);
}

// Wave-coalesced B layout (f16): element at
//   g = ((((i*4 + c)*4 + s)*16 + l15)*4 + quad)*8 + j
// holds f16(We2[k = s*32+quad*8+j][col = i*64 + c*16 + l15]).
__global__ void w2r_kernel(const float* __restrict__ We2,
                           _Float16* __restrict__ w2s) {
  int g = blockIdx.x * 256 + threadIdx.x;  // < 524288
  int j = g & 7;
  int quad = (g >> 3) & 3;
  int l15 = (g >> 5) & 15;
  int s = (g >> 9) & 3;
  int wv = (g >> 11) & 3;
  int i = g >> 13;
  int k = s * 32 + quad * 8 + j;
  int col = i * 64 + wv * 16 + l15;
  w2s[g] = (_Float16)We2[(size_t)k * (OUTD * OUTD) + col];
}

// Fused per-step message kernel, t x i split:
// wave (th, ih) accumulates row-tiles {2th, 2th+1} over i in [32*ih, 32*ih+32)
// for ALL 64 output cols. Each A-scale (h_i * F) feeds 64 cols (4x less VALU
// than col-split) while register state stays small enough for 4 waves/SIMD:
// acc 32 + afr 32 + B-dbuf 32 + misc ~ 120 VGPRs. One-stage LDS reduce
// (partner wv^2 over i-halves), then each wave scatters one 16-row tile.
__global__ __launch_bounds__(256, 4) void msg_kernel(
    const float* __restrict__ h,
    const _Float16* __restrict__ f,
    const _Float16* __restrict__ w2s,
    const int* __restrict__ src,
    const int* __restrict__ dst,
    const float* __restrict__ be2,
    float* __restrict__ agg) {
  // h_t[64][HPAD] floats; after h_t dies the same region is 16KB reduce scratch.
  __shared__ __align__(16) float smem[64 * HPAD];
  __shared__ int s_dst[64];

  const int tid = threadIdx.x;
  const int wv = tid >> 6;
  const int th = wv & 1;   // row-tile half: tiles {2th, 2th+1} (rows 32th..32th+31)
  const int ih = wv >> 1;  // i half: [32*ih, 32*ih+32)
  const int lane = tid & 63;
  const int quad = lane >> 4;
  const int l15 = lane & 15;
  const int e0 = blockIdx.x * 64;

  if (tid < 64) {
    int e = e0 + tid;
    s_dst[tid] = (e < En) ? dst[e] : -1;
  }
  {
    int e = tid & 63;
    int ib = tid >> 6;  // i-block 0..3 (16 i's each)
    int eg = e0 + e;
    int sv = (eg < En) ? src[eg] : 0;
    const float4* hp = reinterpret_cast<const float4*>(h + (size_t)sv * OUTD + ib * 16);
    for (int c = 0; c < 4; ++c) {
      float4 val = hp[c];
      int i4 = ib * 16 + c * 4;
      smem[(i4 + 0) * HPAD + e] = val.x;
      smem[(i4 + 1) * HPAD + e] = val.y;
      smem[(i4 + 2) * HPAD + e] = val.z;
      smem[(i4 + 3) * HPAD + e] = val.w;
    }
  }
  __syncthreads();

  // A-fragments (f16): F rows for this wave's 2 row-tiles x 4 K-steps.
  // A[m=lane&15][k = s*32 + quad*8 + j]
  half8 afr[2][4];
#pragma unroll
  for (int tl = 0; tl < 2; ++tl) {
    int e = e0 + (th * 2 + tl) * 16 + l15;
    if (e >= En) e = En - 1;  // clamped rows suppressed at scatter
    const _Float16* fr = f + (size_t)e * EHID + quad * 8;
#pragma unroll
    for (int s = 0; s < 4; ++s)
      afr[tl][s] = *reinterpret_cast<const half8*>(fr + s * 32);
  }

  const _Float16* w2l = w2s + l15 * 32 + quad * 8;  // lane offset

// load B frags for all 4 col-stripes at (i=II, s=SS) into named buffer B
#define LOADB4(B, II, SS)                                                   \
  {                                                                         \
    const _Float16* p_ = w2l + (size_t)(II) * 8192 + (SS) * 512;            \
    B[0] = *reinterpret_cast<const half8*>(p_);                             \
    B[1] = *reinterpret_cast<const half8*>(p_ + 2048);                      \
    B[2] = *reinterpret_cast<const half8*>(p_ + 4096);                      \
    B[3] = *reinterpret_cast<const half8*>(p_ + 6144);                      \
  }

  floatx4 acc[2][4];  // [local row-tile][col-stripe]
  const floatx4 zero4 = (floatx4){0.f, 0.f, 0.f, 0.f};
#pragma unroll
  for (int tl = 0; tl < 2; ++tl)
#pragma unroll
    for (int c = 0; c < 4; ++c) acc[tl][c] = zero4;

  half8 b0[4], b1[4];
  const int ibase = ih * 32;
  LOADB4(b0, ibase, 0);

// one K-chunk: prefetch next B, scale A by h_i once, feed all 4 col-stripes
#define SSTEP(SS, CURB, NXTB, NI, NS)                                         \
  {                                                                           \
    LOADB4(NXTB, NI, NS);                                                     \
    _Pragma("unroll") for (int tl = 0; tl < 2; ++tl) {                        \
      half8 as = afr[tl][SS] * hb[tl];                                        \
      acc[tl][0] = __builtin_amdgcn_mfma_f32_16x16x32_f16(as, CURB[0], acc[tl][0], 0, 0, 0); \
      acc[tl][1] = __builtin_amdgcn_mfma_f32_16x16x32_f16(as, CURB[1], acc[tl][1], 0, 0, 0); \
      acc[tl][2] = __builtin_amdgcn_mfma_f32_16x16x32_f16(as, CURB[2], acc[tl][2], 0, 0, 0); \
      acc[tl][3] = __builtin_amdgcn_mfma_f32_16x16x32_f16(as, CURB[3], acc[tl][3], 0, 0, 0); \
    }                                                                         \
  }

  for (int ii = 0; ii < 32; ++ii) {
    int iv = ibase + ii;
    half8 hb[2];
#pragma unroll
    for (int tl = 0; tl < 2; ++tl) {
      _Float16 hf = (_Float16)smem[iv * HPAD + (th * 2 + tl) * 16 + l15];
      hb[tl] = (half8){hf, hf, hf, hf, hf, hf, hf, hf};
    }
    int nxi = (ii == 31) ? iv : iv + 1;  // clamp (harmless reload on last iter)
    SSTEP(0, b0, b1, iv, 1);
    SSTEP(1, b1, b0, iv, 2);
    SSTEP(2, b0, b1, iv, 3);
    SSTEP(3, b1, b0, nxi, 0);
  }

  // be2 contribution (exact 0 here, kept for generality). Added once per
  // (row-tile, col) on ih==0 waves BEFORE the i-reduce (h_t still alive),
  // summing all 64 i via two K=32 MFMA chunks.
  if (ih == 0) {
#pragma unroll
    for (int s = 0; s < 2; ++s) {
      half8 b2f[4];
#pragma unroll
      for (int c = 0; c < 4; ++c) {
        half8 v;
#pragma unroll
        for (int j = 0; j < 8; ++j)
          v[j] = (_Float16)be2[(s * 32 + quad * 8 + j) * 64 + c * 16 + l15];
        b2f[c] = v;
      }
#pragma unroll
      for (int tl = 0; tl < 2; ++tl) {
        half8 ha;
#pragma unroll
        for (int j = 0; j < 8; ++j)
          ha[j] = (_Float16)smem[(s * 32 + quad * 8 + j) * HPAD + (th * 2 + tl) * 16 + l15];
#pragma unroll
        for (int c = 0; c < 4; ++c)
          acc[tl][c] = __builtin_amdgcn_mfma_f32_16x16x32_f16(ha, b2f[c], acc[tl][c], 0, 0, 0);
      }
    }
  }

  // ---- one-stage cross-wave reduce over i-halves (partner wv^2), then scatter.
  // ih=0 wave keeps local tile 0 (global 2th), sends local 1; ih=1 keeps
  // local 1 (global 2th+1), sends local 0. Static acc indices only.
  floatx4* scv = reinterpret_cast<floatx4*>(smem);

#define SCAT(TL, T)                                                       \
  {                                                                       \
    int rb = (T) * 16 + quad * 4;                                         \
    _Pragma("unroll") for (int c = 0; c < 4; ++c) {                       \
      int col = c * 16 + l15;                                             \
      _Pragma("unroll") for (int r = 0; r < 4; ++r) {                     \
        int d = s_dst[rb + r];                                            \
        if (d >= 0) atomicAdd(&agg[(size_t)d * OUTD + col], acc[TL][c][r]); \
      }                                                                   \
    }                                                                     \
  }

  __syncthreads();  // h_t dead from here; smem becomes reduce scratch
  if (ih == 0) {
#pragma unroll
    for (int c = 0; c < 4; ++c) scv[wv * 256 + c * 64 + lane] = acc[1][c];
  } else {
#pragma unroll
    for (int c = 0; c < 4; ++c) scv[wv * 256 + c * 64 + lane] = acc[0][c];
  }
  __syncthreads();
  if (ih == 0) {
#pragma unroll
    for (int c = 0; c < 4; ++c) acc[0][c] += scv[(wv ^ 2) * 256 + c * 64 + lane];
    SCAT(0, th * 2);
  } else {
#pragma unroll
    for (int c = 0; c < 4; ++c) acc[1][c] += scv[(wv ^ 2) * 256 + c * 64 + lane];
    SCAT(1, th * 2 + 1);
  }
}

// h_out = relu(agg + bias); re-zero agg; last step also writes fp32 d_out
__global__ void update_kernel(float* __restrict__ agg,
                              const float* __restrict__ bias,
                              float* __restrict__ hout,
                              float* __restrict__ dout, int last) {
  int g = blockIdx.x * 256 + threadIdx.x;
  if (g >= Vn * OUTD) return;
  float v = agg[g];
  agg[g] = 0.0f;
  float r = fmaxf(v + bias[g & 63], 0.0f);
  hout[g] = r;
  if (last) dout[g] = r;
}

extern "C" void kernel_launch(void* const* d_in, const int* in_sizes, int n_in,
                              void* d_out, int out_size, void* d_ws, size_t ws_size,
                              hipStream_t stream) {
  const float* node = (const float*)d_in[0];
  const float* edge = (const float*)d_in[1];
  const int* src = (const int*)d_in[2];
  const int* dst = (const int*)d_in[3];
  const float* Wp   = (const float*)d_in[4];
  const float* bp   = (const float*)d_in[5];
  const float* We1  = (const float*)d_in[6];
  const float* be1  = (const float*)d_in[7];
  const float* We2  = (const float*)d_in[8];
  const float* be2  = (const float*)d_in[9];
  const float* bias = (const float*)d_in[10];
  float* out = (float*)d_out;

  char* ws = (char*)d_ws;
  float* agg = (float*)(ws);                        // 6,400,000 B
  float* h_a = (float*)(ws + 6400000);              // 6,400,000 B
  float* h_b = (float*)(ws + 12800000);             // 6,400,000 B
  _Float16* f   = (_Float16*)(ws + 19200000);       // 25,600,000 B
  _Float16* w2s = (_Float16*)(ws + 44800000);       // 1,048,576 B

  hipMemsetAsync(agg, 0, (size_t)Vn * OUTD * sizeof(float), stream);
  proj_kernel<<<Vn, 64, 0, stream>>>(node, Wp, bp, h_a);
  edge_kernel<<<En, 128, 0, stream>>>(edge, We1, be1, f);
  w2r_kernel<<<(OUTD * OUTD * EHID) / 256, 256, 0, stream>>>(We2, w2s);

  float* hin = h_a;
  float* hout = h_b;
  for (int s = 0; s < NUM_STEPS; ++s) {
    msg_kernel<<<(En + 63) / 64, 256, 0, stream>>>(hin, f, w2s, src, dst, be2, agg);
    update_kernel<<<(Vn * OUTD + 255) / 256, 256, 0, stream>>>(
        agg, bias, hout, out, s == NUM_STEPS - 1);
    float* t = hin; hin = hout; hout = t;
  }
}

// Round 5
// 1002.964 us; speedup vs baseline: 1.4434x; 1.4434x over previous
//
#include <hip/hip_runtime.h>
#include <hip/hip_bf16.h>

#define Vn 25000
#define En 100000
#define NODE_IN 74
#define EDGE_IN 12
#define OUTD 64
#define EHID 128
#define NUM_STEPS 6

#define HPAD 68  // h_t row pitch (floats)

typedef __attribute__((ext_vector_type(8))) _Float16 half8;
typedef __attribute__((ext_vector_type(4))) float floatx4;

// h[v,o] = relu(node[v,:] @ Wp + bp)   [V,74]@[74,64]  (all fp32)
__global__ void proj_kernel(const float* __restrict__ node,
                            const float* __restrict__ Wp,
                            const float* __restrict__ bp,
                            float* __restrict__ h) {
  __shared__ float nf[NODE_IN];
  int v = blockIdx.x;
  int o = threadIdx.x;  // 64
  for (int i = o; i < NODE_IN; i += 64) nf[i] = node[(size_t)v * NODE_IN + i];
  __syncthreads();
  float acc = bp[o];
  for (int i = 0; i < NODE_IN; ++i) acc = fmaf(nf[i], Wp[i * OUTD + o], acc);
  h[(size_t)v * OUTD + o] = fmaxf(acc, 0.0f);
}

// f[e,k] = relu(edge[e,:] @ We1 + be1)   [E,12]@[12,128] fp32, stored f16
__global__ void edge_kernel(const float* __restrict__ ef,
                            const float* __restrict__ We1,
                            const float* __restrict__ be1,
                            _Float16* __restrict__ f) {
  __shared__ float es[EDGE_IN];
  int e = blockIdx.x;
  int k = threadIdx.x;  // 128
  if (k < EDGE_IN) es[k] = ef[(size_t)e * EDGE_IN + k];
  __syncthreads();
  float acc = be1[k];
  for (int j = 0; j < EDGE_IN; ++j) acc = fmaf(es[j], We1[j * EHID + k], acc);
  f[(size_t)e * EHID + k] = (_Float16)fmaxf(acc, 0.0f);
}

// SSTEP-contiguous B layout (f16): element at
//   g = step*2048 + c*512 + l15*32 + quad*8 + j,   step = i*4 + s
// holds f16(We2[k = s*32+quad*8+j][col = i*64 + c*16 + l15]).
// One SSTEP = one contiguous 4KB chunk (all 4 col-stripes) -> single base
// per SSTEP, imm offsets 0/1024/2048/3072B for the 4 fragment loads.
__global__ void w2r_kernel(const float* __restrict__ We2,
                           _Float16* __restrict__ w2s) {
  int g = blockIdx.x * 256 + threadIdx.x;  // < 524288
  int j = g & 7;
  int quad = (g >> 3) & 3;
  int l15 = (g >> 5) & 15;
  int c = (g >> 9) & 3;
  int step = g >> 11;     // 0..255
  int s = step & 3;
  int i = step >> 2;
  int k = s * 32 + quad * 8 + j;
  int col = i * 64 + c * 16 + l15;
  w2s[g] = (_Float16)We2[(size_t)k * (OUTD * OUTD) + col];
}

// Fused per-step message kernel, i-split across waves (round-2 structure)
// + prefetch distance 3 via 4 named B register buffers + SSTEP-contiguous
// B layout. Wave w accumulates over i in [16w,16w+16) for ALL 64 output
// cols (minimal rank-1 scale VALU); two-stage LDS reduce; atomic scatter.
__global__ __launch_bounds__(256, 2) void msg_kernel(
    const float* __restrict__ h,
    const _Float16* __restrict__ f,
    const _Float16* __restrict__ w2s,
    const int* __restrict__ src,
    const int* __restrict__ dst,
    const float* __restrict__ be2,
    float* __restrict__ agg) {
  // first 4352 floats: h_t[64][HPAD]; after h_t dies: 32KB reduce scratch.
  __shared__ __align__(16) float smem[8192];
  __shared__ int s_dst[64];

  const int tid = threadIdx.x;
  const int wv = tid >> 6;        // wave 0..3 -> i-subset [16wv,16wv+16)
  const int lane = tid & 63;
  const int quad = lane >> 4;
  const int l15 = lane & 15;
  const int e0 = blockIdx.x * 64;

  if (tid < 64) {
    int e = e0 + tid;
    s_dst[tid] = (e < En) ? dst[e] : -1;
  }
  {
    int e = tid & 63;
    int ib = tid >> 6;  // i-block 0..3 (16 i's each)
    int eg = e0 + e;
    int sv = (eg < En) ? src[eg] : 0;
    const float4* hp = reinterpret_cast<const float4*>(h + (size_t)sv * OUTD + ib * 16);
    for (int c = 0; c < 4; ++c) {
      float4 val = hp[c];
      int i4 = ib * 16 + c * 4;
      smem[(i4 + 0) * HPAD + e] = val.x;
      smem[(i4 + 1) * HPAD + e] = val.y;
      smem[(i4 + 2) * HPAD + e] = val.z;
      smem[(i4 + 3) * HPAD + e] = val.w;
    }
  }
  __syncthreads();

  // A-fragments (f16): F rows for 4 row-tiles x 4 K-steps (i-invariant).
  // A[m=lane&15][k = s*32 + quad*8 + j]
  half8 afr[4][4];
#pragma unroll
  for (int t = 0; t < 4; ++t) {
    int e = e0 + t * 16 + l15;
    if (e >= En) e = En - 1;  // clamped rows suppressed at scatter
    const _Float16* fr = f + (size_t)e * EHID + quad * 8;
#pragma unroll
    for (int s = 0; s < 4; ++s)
      afr[t][s] = *reinterpret_cast<const half8*>(fr + s * 32);
  }

  const _Float16* w2l = w2s + l15 * 32 + quad * 8;  // lane offset

// load the 4 col-stripe frags of SSTEP index STEP into named buffer B.
// One per-SSTEP base; c-strides are 512 halves = 1KB imm offsets.
#define LOADB4(B, STEP)                                                     \
  {                                                                         \
    const _Float16* p_ = w2l + (size_t)(STEP) * 2048;                       \
    B[0] = *reinterpret_cast<const half8*>(p_);                             \
    B[1] = *reinterpret_cast<const half8*>(p_ + 512);                       \
    B[2] = *reinterpret_cast<const half8*>(p_ + 1024);                      \
    B[3] = *reinterpret_cast<const half8*>(p_ + 1536);                      \
  }

  floatx4 acc[4][4];  // [row-tile t][col-stripe c]
  const floatx4 zero4 = (floatx4){0.f, 0.f, 0.f, 0.f};
#pragma unroll
  for (int t = 0; t < 4; ++t)
#pragma unroll
    for (int c = 0; c < 4; ++c) acc[t][c] = zero4;

  const int ibase = wv * 16;
  const int sbase = ibase * 4;     // first SSTEP index for this wave
  const int smax = sbase + 63;     // last SSTEP index

  half8 B0[4], B1[4], B2[4], B3[4];
  LOADB4(B0, sbase);
  LOADB4(B1, sbase + 1);
  LOADB4(B2, sbase + 2);

// one K-chunk: prefetch SSTEP (sb+SS+3) into PF (the buffer consumed last
// SSTEP), scale A by h_i once, feed all 4 col-stripes from USE.
#define SSTEP(SS, USE, PF)                                                    \
  {                                                                           \
    int ps_ = sb + (SS) + 3;                                                  \
    if (ps_ > smax) ps_ = smax; /* tail: harmless reload, data unused */      \
    LOADB4(PF, ps_);                                                          \
    _Pragma("unroll") for (int t = 0; t < 4; ++t) {                           \
      half8 as = afr[t][SS] * hb[t];                                          \
      acc[t][0] = __builtin_amdgcn_mfma_f32_16x16x32_f16(as, USE[0], acc[t][0], 0, 0, 0); \
      acc[t][1] = __builtin_amdgcn_mfma_f32_16x16x32_f16(as, USE[1], acc[t][1], 0, 0, 0); \
      acc[t][2] = __builtin_amdgcn_mfma_f32_16x16x32_f16(as, USE[2], acc[t][2], 0, 0, 0); \
      acc[t][3] = __builtin_amdgcn_mfma_f32_16x16x32_f16(as, USE[3], acc[t][3], 0, 0, 0); \
    }                                                                         \
  }

  for (int ii = 0; ii < 16; ++ii) {
    int iv = ibase + ii;
    int sb = iv * 4;
    half8 hb[4];
#pragma unroll
    for (int t = 0; t < 4; ++t) {
      _Float16 hf = (_Float16)smem[iv * HPAD + t * 16 + l15];
      hb[t] = (half8){hf, hf, hf, hf, hf, hf, hf, hf};
    }
    SSTEP(0, B0, B3);
    SSTEP(1, B1, B0);
    SSTEP(2, B2, B1);
    SSTEP(3, B3, B2);
  }

  // be2 contribution (exact 0 here, kept for generality): wave 0 owns all
  // cols pre-reduction, so add sum_i h[e,i]*be2[i*64+o] on wave 0 only.
  if (wv == 0) {
#pragma unroll
    for (int s = 0; s < 2; ++s) {
      half8 b2f[4];
#pragma unroll
      for (int c = 0; c < 4; ++c) {
        half8 v;
#pragma unroll
        for (int j = 0; j < 8; ++j)
          v[j] = (_Float16)be2[(s * 32 + quad * 8 + j) * 64 + c * 16 + l15];
        b2f[c] = v;
      }
#pragma unroll
      for (int t = 0; t < 4; ++t) {
        half8 ha;
#pragma unroll
        for (int j = 0; j < 8; ++j)
          ha[j] = (_Float16)smem[(s * 32 + quad * 8 + j) * HPAD + t * 16 + l15];
#pragma unroll
        for (int c = 0; c < 4; ++c)
          acc[t][c] = __builtin_amdgcn_mfma_f32_16x16x32_f16(ha, b2f[c], acc[t][c], 0, 0, 0);
      }
    }
  }

  // ---- two-stage cross-wave reduce over i-quarters, then scatter.
  floatx4* scv = reinterpret_cast<floatx4*>(smem);

#define ST1(TG)                                                           \
  _Pragma("unroll") for (int c = 0; c < 4; ++c)                           \
      scv[wv * 512 + (((TG) & 1) * 4 + c) * 64 + lane] = acc[TG][c];
#define LD1(TK)                                                           \
  _Pragma("unroll") for (int c = 0; c < 4; ++c)                           \
      acc[TK][c] += scv[(wv ^ 1) * 512 + (((TK) & 1) * 4 + c) * 64 + lane];
#define ST2(TG)                                                           \
  _Pragma("unroll") for (int c = 0; c < 4; ++c)                           \
      scv[wv * 512 + c * 64 + lane] = acc[TG][c];
#define LD2(TK)                                                           \
  _Pragma("unroll") for (int c = 0; c < 4; ++c)                           \
      acc[TK][c] += scv[(wv ^ 2) * 512 + c * 64 + lane];
#define SCAT(TF)                                                          \
  {                                                                       \
    int rb = (TF) * 16 + quad * 4;                                        \
    _Pragma("unroll") for (int c = 0; c < 4; ++c) {                       \
      int col = c * 16 + l15;                                             \
      _Pragma("unroll") for (int r = 0; r < 4; ++r) {                     \
        int d = s_dst[rb + r];                                            \
        if (d >= 0) atomicAdd(&agg[(size_t)d * OUTD + col], acc[TF][c][r]); \
      }                                                                   \
    }                                                                     \
  }

  __syncthreads();  // h_t dead from here; smem becomes reduce scratch
  // stage 1: pairs (0,1),(2,3). even wave keeps rows t{0,1}, odd keeps t{2,3}
  if ((wv & 1) == 0) { ST1(2); ST1(3); } else { ST1(0); ST1(1); }
  __syncthreads();
  if ((wv & 1) == 0) { LD1(0); LD1(1); } else { LD1(2); LD1(3); }
  __syncthreads();
  // stage 2: pairs (0,2),(1,3). final tile: w0->t0, w2->t1, w1->t2, w3->t3
  if (wv == 0) { ST2(1); } else if (wv == 1) { ST2(3); }
  else if (wv == 2) { ST2(0); } else { ST2(2); }
  __syncthreads();
  if (wv == 0) { LD2(0); SCAT(0); }
  else if (wv == 1) { LD2(2); SCAT(2); }
  else if (wv == 2) { LD2(1); SCAT(1); }
  else { LD2(3); SCAT(3); }
}

// h_out = relu(agg + bias); re-zero agg; last step also writes fp32 d_out
__global__ void update_kernel(float* __restrict__ agg,
                              const float* __restrict__ bias,
                              float* __restrict__ hout,
                              float* __restrict__ dout, int last) {
  int g = blockIdx.x * 256 + threadIdx.x;
  if (g >= Vn * OUTD) return;
  float v = agg[g];
  agg[g] = 0.0f;
  float r = fmaxf(v + bias[g & 63], 0.0f);
  hout[g] = r;
  if (last) dout[g] = r;
}

extern "C" void kernel_launch(void* const* d_in, const int* in_sizes, int n_in,
                              void* d_out, int out_size, void* d_ws, size_t ws_size,
                              hipStream_t stream) {
  const float* node = (const float*)d_in[0];
  const float* edge = (const float*)d_in[1];
  const int* src = (const int*)d_in[2];
  const int* dst = (const int*)d_in[3];
  const float* Wp   = (const float*)d_in[4];
  const float* bp   = (const float*)d_in[5];
  const float* We1  = (const float*)d_in[6];
  const float* be1  = (const float*)d_in[7];
  const float* We2  = (const float*)d_in[8];
  const float* be2  = (const float*)d_in[9];
  const float* bias = (const float*)d_in[10];
  float* out = (float*)d_out;

  char* ws = (char*)d_ws;
  float* agg = (float*)(ws);                        // 6,400,000 B
  float* h_a = (float*)(ws + 6400000);              // 6,400,000 B
  float* h_b = (float*)(ws + 12800000);              // 6,400,000 B
  _Float16* f   = (_Float16*)(ws + 19200000);       // 25,600,000 B
  _Float16* w2s = (_Float16*)(ws + 44800000);       // 1,048,576 B

  hipMemsetAsync(agg, 0, (size_t)Vn * OUTD * sizeof(float), stream);
  proj_kernel<<<Vn, 64, 0, stream>>>(node, Wp, bp, h_a);
  edge_kernel<<<En, 128, 0, stream>>>(edge, We1, be1, f);
  w2r_kernel<<<(OUTD * OUTD * EHID) / 256, 256, 0, stream>>>(We2, w2s);

  float* hin = h_a;
  float* hout = h_b;
  for (int s = 0; s < NUM_STEPS; ++s) {
    msg_kernel<<<(En + 63) / 64, 256, 0, stream>>>(hin, f, w2s, src, dst, be2, agg);
    update_kernel<<<(Vn * OUTD + 255) / 256, 256, 0, stream>>>(
        agg, bias, hout, out, s == NUM_STEPS - 1);
    float* t = hin; hin = hout; hout = t;
  }
}

// Round 7
// 810.059 us; speedup vs baseline: 1.7872x; 1.2381x over previous
//
#include <hip/hip_runtime.h>
#include <hip/hip_bf16.h>

#define Vn 25000
#define En 100000
#define NODE_IN 74
#define EDGE_IN 12
#define OUTD 64
#define EHID 128
#define NUM_STEPS 6

#define HPAD 68  // h_t row pitch (floats)

typedef __attribute__((ext_vector_type(8))) _Float16 half8;
typedef __attribute__((ext_vector_type(4))) float floatx4;

// h[v,o] = relu(node[v,:] @ Wp + bp)   [V,74]@[74,64]  (all fp32)
__global__ void proj_kernel(const float* __restrict__ node,
                            const float* __restrict__ Wp,
                            const float* __restrict__ bp,
                            float* __restrict__ h) {
  __shared__ float nf[NODE_IN];
  int v = blockIdx.x;
  int o = threadIdx.x;  // 64
  for (int i = o; i < NODE_IN; i += 64) nf[i] = node[(size_t)v * NODE_IN + i];
  __syncthreads();
  float acc = bp[o];
  for (int i = 0; i < NODE_IN; ++i) acc = fmaf(nf[i], Wp[i * OUTD + o], acc);
  h[(size_t)v * OUTD + o] = fmaxf(acc, 0.0f);
}

// f[e,k] = relu(edge[e,:] @ We1 + be1)   [E,12]@[12,128] fp32, stored f16
__global__ void edge_kernel(const float* __restrict__ ef,
                            const float* __restrict__ We1,
                            const float* __restrict__ be1,
                            _Float16* __restrict__ f) {
  __shared__ float es[EDGE_IN];
  int e = blockIdx.x;
  int k = threadIdx.x;  // 128
  if (k < EDGE_IN) es[k] = ef[(size_t)e * EDGE_IN + k];
  __syncthreads();
  float acc = be1[k];
  for (int j = 0; j < EDGE_IN; ++j) acc = fmaf(es[j], We1[j * EHID + k], acc);
  f[(size_t)e * EHID + k] = (_Float16)fmaxf(acc, 0.0f);
}

// SSTEP-contiguous + bank-swizzled B layout (f16).
// Logical index: g = step*2048 + c*512 + l15*32 + quad*8 + j, step = i*4+s,
// value = f16(We2[k = s*32+quad*8+j][col = i*64 + c*16 + l15]).
// Stored at step*2048 + (eidx ^ ((eidx>>6 & 3) << 3))  (quad ^= l15[2:1]):
// makes the per-stripe ds_read_b128 (16 lanes at 64B stride) hit all 32
// banks 2-way (free) instead of 8-way. global_load_lds stages each 4KB
// step-chunk linearly, so the swizzle is pre-baked in the global image
// and the reader applies the same XOR to its byte offset.
__global__ void w2r_kernel(const float* __restrict__ We2,
                           _Float16* __restrict__ w2s) {
  int g = blockIdx.x * 256 + threadIdx.x;  // < 524288 (logical index)
  int j = g & 7;
  int quad = (g >> 3) & 3;
  int l15 = (g >> 5) & 15;
  int c = (g >> 9) & 3;
  int step = g >> 11;     // 0..255
  int s = step & 3;
  int i = step >> 2;
  int k = s * 32 + quad * 8 + j;
  int col = i * 64 + c * 16 + l15;
  int eidx = g & 2047;
  int estore = eidx ^ (((eidx >> 6) & 3) << 3);
  w2s[((size_t)step << 11) | estore] = (_Float16)We2[(size_t)k * (OUTD * OUTD) + col];
}

#define GLOAD_LDS(gp, lp)                                                     \
  __builtin_amdgcn_global_load_lds(                                           \
      (const __attribute__((address_space(1))) void*)(gp),                    \
      (__attribute__((address_space(3))) void*)(lp), 16, 0, 0)

// Fused per-step message kernel, i-split across waves:
// wave w accumulates over i in [16w,16w+16) for ALL 64 output cols
// (minimal rank-1 scale VALU). B is streamed via global_load_lds into a
// per-wave private 2-slot LDS ring (4KB/step-chunk) with counted
// s_waitcnt vmcnt(4) — deep HW load queue, zero buffer VGPRs, no K-loop
// barriers. RACE FIX vs prev round: explicit s_waitcnt lgkmcnt(0) +
// sched_barrier(0) BEFORE re-staging a slot, so the slot's ds_reads have
// architecturally retired before the DMA write to the same LDS addresses
// can be issued (compiler was free to issue the DMA before its own lgkm
// wait; DS-pipe reads vs LDS-DMA writes have no HW ordering guarantee).
__global__ __launch_bounds__(256, 3) void msg_kernel(
    const float* __restrict__ h,
    const _Float16* __restrict__ f,
    const _Float16* __restrict__ w2s,
    const int* __restrict__ src,
    const int* __restrict__ dst,
    const float* __restrict__ be2,
    float* __restrict__ agg) {
  // [0,4352) floats: h_t[64][HPAD]; [4352,12544): per-wave B rings (4 x 8KB).
  // Epilogue reuses [0,8188) floats as reduce scratch (everything dead then).
  __shared__ __align__(16) float smem[12544];
  __shared__ int s_dst[64];

  const int tid = threadIdx.x;
  const int wv = tid >> 6;        // wave 0..3 -> i-subset [16wv,16wv+16)
  const int lane = tid & 63;
  const int quad = lane >> 4;
  const int l15 = lane & 15;
  const int e0 = blockIdx.x * 64;

  if (tid < 64) {
    int e = e0 + tid;
    s_dst[tid] = (e < En) ? dst[e] : -1;
  }
  {
    int e = tid & 63;
    int ib = tid >> 6;  // i-block 0..3 (16 i's each)
    int eg = e0 + e;
    int sv = (eg < En) ? src[eg] : 0;
    const float4* hp = reinterpret_cast<const float4*>(h + (size_t)sv * OUTD + ib * 16);
    for (int c = 0; c < 4; ++c) {
      float4 val = hp[c];
      int i4 = ib * 16 + c * 4;
      smem[(i4 + 0) * HPAD + e] = val.x;
      smem[(i4 + 1) * HPAD + e] = val.y;
      smem[(i4 + 2) * HPAD + e] = val.z;
      smem[(i4 + 3) * HPAD + e] = val.w;
    }
  }
  __syncthreads();

  // A-fragments (f16): F rows for 4 row-tiles x 4 K-steps (i-invariant).
  // A[m=lane&15][k = s*32 + quad*8 + j]
  half8 afr[4][4];
#pragma unroll
  for (int t = 0; t < 4; ++t) {
    int e = e0 + t * 16 + l15;
    if (e >= En) e = En - 1;  // clamped rows suppressed at scatter
    const _Float16* fr = f + (size_t)e * EHID + quad * 8;
#pragma unroll
    for (int s = 0; s < 4; ++s)
      afr[t][s] = *reinterpret_cast<const half8*>(fr + s * 32);
  }

  floatx4 acc[4][4];  // [row-tile t][col-stripe c]
  const floatx4 zero4 = (floatx4){0.f, 0.f, 0.f, 0.f};
#pragma unroll
  for (int t = 0; t < 4; ++t)
#pragma unroll
    for (int c = 0; c < 4; ++c) acc[t][c] = zero4;

  const int ibase = wv * 16;

  // per-wave private ring: 2 slots x 4KB
  char* ring = (char*)smem + 4352 * 4 + wv * 8192;
  const char* w2b = (const char*)w2s;
  // swizzled per-lane byte offset within a 4KB chunk (stripe c adds c*1024)
  const int roff = l15 * 64 + ((quad ^ ((l15 >> 1) & 3)) << 4);
  const char* slot0p = ring + roff;
  const char* slot1p = ring + 4096 + roff;

// stage global step GS (4KB) into ring slot SLOT: 4 x global_load_lds width-16
#define STAGE(GS, SLOT)                                                       \
  {                                                                           \
    const char* gp_ = w2b + (size_t)(GS) * 4096 + lane * 16;                  \
    char* lp_ = ring + (SLOT) * 4096;                                         \
    GLOAD_LDS(gp_, lp_);                                                      \
    GLOAD_LDS(gp_ + 1024, lp_ + 1024);                                        \
    GLOAD_LDS(gp_ + 2048, lp_ + 2048);                                        \
    GLOAD_LDS(gp_ + 3072, lp_ + 3072);                                        \
  }

#define VM4 asm volatile("s_waitcnt vmcnt(4)" ::: "memory")
#define VM0 asm volatile("s_waitcnt vmcnt(0)" ::: "memory")
#define LGKM0 asm volatile("s_waitcnt lgkmcnt(0)" ::: "memory")

// one K-chunk: wait for this slot's chunk (vmcnt retires in issue order,
// so outstanding<=4 => this slot's 4 DMA writes landed), read 4 stripes
// (b128, swizzled), DRAIN the reads (lgkmcnt(0) + sched_barrier so the
// re-stage DMA cannot be issued before the reads retire), re-stage step
// GS+2 into the same slot, then scale A once per tile and run 16 MFMAs.
#define KSTEP(SS, SLOTP, SLOT, WAIT, DOSTAGE, IV)                             \
  {                                                                           \
    WAIT;                                                                     \
    half8 b0_ = *reinterpret_cast<const half8*>(SLOTP);                       \
    half8 b1_ = *reinterpret_cast<const half8*>(SLOTP + 1024);                \
    half8 b2_ = *reinterpret_cast<const half8*>(SLOTP + 2048);                \
    half8 b3_ = *reinterpret_cast<const half8*>(SLOTP + 3072);                \
    LGKM0;                                                                    \
    __builtin_amdgcn_sched_barrier(0);                                        \
    if (DOSTAGE) STAGE(((IV) << 2) + (SS) + 2, SLOT);                         \
    _Pragma("unroll") for (int t = 0; t < 4; ++t) {                           \
      half8 as = afr[t][SS] * hb[t];                                          \
      acc[t][0] = __builtin_amdgcn_mfma_f32_16x16x32_f16(as, b0_, acc[t][0], 0, 0, 0); \
      acc[t][1] = __builtin_amdgcn_mfma_f32_16x16x32_f16(as, b1_, acc[t][1], 0, 0, 0); \
      acc[t][2] = __builtin_amdgcn_mfma_f32_16x16x32_f16(as, b2_, acc[t][2], 0, 0, 0); \
      acc[t][3] = __builtin_amdgcn_mfma_f32_16x16x32_f16(as, b3_, acc[t][3], 0, 0, 0); \
    }                                                                         \
  }

#define BUILD_HB(IV)                                                          \
  half8 hb[4];                                                                \
  _Pragma("unroll") for (int t = 0; t < 4; ++t) {                             \
    _Float16 hf = (_Float16)smem[(IV) * HPAD + t * 16 + l15];                 \
    hb[t] = (half8){hf, hf, hf, hf, hf, hf, hf, hf};                          \
  }

  // prologue: stage first two chunks of this wave's range
  STAGE(ibase * 4, 0);
  STAGE(ibase * 4 + 1, 1);

  for (int ii = 0; ii < 15; ++ii) {
    int iv = ibase + ii;
    BUILD_HB(iv);
    KSTEP(0, slot0p, 0, VM4, 1, iv);
    KSTEP(1, slot1p, 1, VM4, 1, iv);
    KSTEP(2, slot0p, 0, VM4, 1, iv);
    KSTEP(3, slot1p, 1, VM4, 1, iv);
  }
  {  // peeled last i: steps 62,63 have nothing to stage; final wait is vmcnt(0)
    int iv = ibase + 15;
    BUILD_HB(iv);
    KSTEP(0, slot0p, 0, VM4, 1, iv);
    KSTEP(1, slot1p, 1, VM4, 1, iv);
    KSTEP(2, slot0p, 0, VM4, 0, iv);
    KSTEP(3, slot1p, 1, VM0, 0, iv);
  }

  // be2 contribution (exact 0 here, kept for generality): wave 0 owns all
  // cols pre-reduction, so add sum_i h[e,i]*be2[i*64+o] on wave 0 only.
  if (wv == 0) {
#pragma unroll
    for (int s = 0; s < 2; ++s) {
      half8 b2f[4];
#pragma unroll
      for (int c = 0; c < 4; ++c) {
        half8 v;
#pragma unroll
        for (int j = 0; j < 8; ++j)
          v[j] = (_Float16)be2[(s * 32 + quad * 8 + j) * 64 + c * 16 + l15];
        b2f[c] = v;
      }
#pragma unroll
      for (int t = 0; t < 4; ++t) {
        half8 ha;
#pragma unroll
        for (int j = 0; j < 8; ++j)
          ha[j] = (_Float16)smem[(s * 32 + quad * 8 + j) * HPAD + t * 16 + l15];
#pragma unroll
        for (int c = 0; c < 4; ++c)
          acc[t][c] = __builtin_amdgcn_mfma_f32_16x16x32_f16(ha, b2f[c], acc[t][c], 0, 0, 0);
      }
    }
  }

  // ---- two-stage cross-wave reduce over i-quarters, then scatter.
  floatx4* scv = reinterpret_cast<floatx4*>(smem);

#define ST1(TG)                                                           \
  _Pragma("unroll") for (int c = 0; c < 4; ++c)                           \
      scv[wv * 512 + (((TG) & 1) * 4 + c) * 64 + lane] = acc[TG][c];
#define LD1(TK)                                                           \
  _Pragma("unroll") for (int c = 0; c < 4; ++c)                           \
      acc[TK][c] += scv[(wv ^ 1) * 512 + (((TK) & 1) * 4 + c) * 64 + lane];
#define ST2(TG)                                                           \
  _Pragma("unroll") for (int c = 0; c < 4; ++c)                           \
      scv[wv * 512 + c * 64 + lane] = acc[TG][c];
#define LD2(TK)                                                           \
  _Pragma("unroll") for (int c = 0; c < 4; ++c)                           \
      acc[TK][c] += scv[(wv ^ 2) * 512 + c * 64 + lane];
#define SCAT(TF)                                                          \
  {                                                                       \
    int rb = (TF) * 16 + quad * 4;                                        \
    _Pragma("unroll") for (int c = 0; c < 4; ++c) {                       \
      int col = c * 16 + l15;                                             \
      _Pragma("unroll") for (int r = 0; r < 4; ++r) {                     \
        int d = s_dst[rb + r];                                            \
        if (d >= 0) atomicAdd(&agg[(size_t)d * OUTD + col], acc[TF][c][r]); \
      }                                                                   \
    }                                                                     \
  }

  __syncthreads();  // h_t and rings dead from here; smem becomes scratch
  // stage 1: pairs (0,1),(2,3). even wave keeps rows t{0,1}, odd keeps t{2,3}
  if ((wv & 1) == 0) { ST1(2); ST1(3); } else { ST1(0); ST1(1); }
  __syncthreads();
  if ((wv & 1) == 0) { LD1(0); LD1(1); } else { LD1(2); LD1(3); }
  __syncthreads();
  // stage 2: pairs (0,2),(1,3). final tile: w0->t0, w2->t1, w1->t2, w3->t3
  if (wv == 0) { ST2(1); } else if (wv == 1) { ST2(3); }
  else if (wv == 2) { ST2(0); } else { ST2(2); }
  __syncthreads();
  if (wv == 0) { LD2(0); SCAT(0); }
  else if (wv == 1) { LD2(2); SCAT(2); }
  else if (wv == 2) { LD2(1); SCAT(1); }
  else { LD2(3); SCAT(3); }
}

// h_out = relu(agg + bias); re-zero agg; last step also writes fp32 d_out
__global__ void update_kernel(float* __restrict__ agg,
                              const float* __restrict__ bias,
                              float* __restrict__ hout,
                              float* __restrict__ dout, int last) {
  int g = blockIdx.x * 256 + threadIdx.x;
  if (g >= Vn * OUTD) return;
  float v = agg[g];
  agg[g] = 0.0f;
  float r = fmaxf(v + bias[g & 63], 0.0f);
  hout[g] = r;
  if (last) dout[g] = r;
}

extern "C" void kernel_launch(void* const* d_in, const int* in_sizes, int n_in,
                              void* d_out, int out_size, void* d_ws, size_t ws_size,
                              hipStream_t stream) {
  const float* node = (const float*)d_in[0];
  const float* edge = (const float*)d_in[1];
  const int* src = (const int*)d_in[2];
  const int* dst = (const int*)d_in[3];
  const float* Wp   = (const float*)d_in[4];
  const float* bp   = (const float*)d_in[5];
  const float* We1  = (const float*)d_in[6];
  const float* be1  = (const float*)d_in[7];
  const float* We2  = (const float*)d_in[8];
  const float* be2  = (const float*)d_in[9];
  const float* bias = (const float*)d_in[10];
  float* out = (float*)d_out;

  char* ws = (char*)d_ws;
  float* agg = (float*)(ws);                        // 6,400,000 B
  float* h_a = (float*)(ws + 6400000);              // 6,400,000 B
  float* h_b = (float*)(ws + 12800000);             // 6,400,000 B
  _Float16* f   = (_Float16*)(ws + 19200000);       // 25,600,000 B
  _Float16* w2s = (_Float16*)(ws + 44800000);       // 1,048,576 B

  hipMemsetAsync(agg, 0, (size_t)Vn * OUTD * sizeof(float), stream);
  proj_kernel<<<Vn, 64, 0, stream>>>(node, Wp, bp, h_a);
  edge_kernel<<<En, 128, 0, stream>>>(edge, We1, be1, f);
  w2r_kernel<<<(OUTD * OUTD * EHID) / 256, 256, 0, stream>>>(We2, w2s);

  float* hin = h_a;
  float* hout = h_b;
  for (int s = 0; s < NUM_STEPS; ++s) {
    msg_kernel<<<(En + 63) / 64, 256, 0, stream>>>(hin, f, w2s, src, dst, be2, agg);
    update_kernel<<<(Vn * OUTD + 255) / 256, 256, 0, stream>>>(
        agg, bias, hout, out, s == NUM_STEPS - 1);
    float* t = hin; hin = hout; hout = t;
  }
}